// Round 3
// baseline (573.529 us; speedup 1.0000x reference)
//
#include <hip/hip_runtime.h>

#define H 1024
#define W 1024
#define NIMG 32
#define NOFF 16
#define NACC 17          // 16 cross terms + 1 sum(s^2)
#define TH 64            // owned rows per block
#define TW 256           // owned cols per block
#define TROWS 71         // TH + 7 halo rows (down only)
#define TSTR 304         // LDS row stride bytes: 16 left pad + 256 + 32 right pad
#define NTHR 512
#define NWAVE 8
#define NBLK (W / TW * (H / TH) * NIMG)   // 2048 glcm blocks

__device__ __forceinline__ int sdot4i(unsigned a, unsigned b, int c) {
#if __has_builtin(__builtin_amdgcn_sdot4)
    return __builtin_amdgcn_sdot4((int)a, (int)b, c, false);
#else
    c += (int)(signed char)(a)       * (int)(signed char)(b);
    c += (int)(signed char)(a >> 8)  * (int)(signed char)(b >> 8);
    c += (int)(signed char)(a >> 16) * (int)(signed char)(b >> 16);
    c += (int)(signed char)(a >> 24) * (int)(signed char)(b >> 24);
    return c;
#endif
}

__device__ __forceinline__ unsigned funnel(unsigned hi, unsigned lo, int shiftBytes) {
#if __has_builtin(__builtin_amdgcn_alignbit)
    return __builtin_amdgcn_alignbit(hi, lo, shiftBytes * 8);
#else
    unsigned long long pair = (((unsigned long long)hi) << 32) | lo;
    return (unsigned)(pair >> (shiftBytes * 8));
#endif
}

// wave64 sum via DPP butterfly: total lands in lane 63 (pure VALU, no LDS).
__device__ __forceinline__ int wave_sum(int v) {
    v += __builtin_amdgcn_update_dpp(0, v, 0x111, 0xf, 0xf, false); // row_shr:1
    v += __builtin_amdgcn_update_dpp(0, v, 0x112, 0xf, 0xf, false); // row_shr:2
    v += __builtin_amdgcn_update_dpp(0, v, 0x114, 0xf, 0xf, false); // row_shr:4
    v += __builtin_amdgcn_update_dpp(0, v, 0x118, 0xf, 0xf, false); // row_shr:8
    v += __builtin_amdgcn_update_dpp(0, v, 0x142, 0xa, 0xf, false); // row_bcast:15
    v += __builtin_amdgcn_update_dpp(0, v, 0x143, 0xc, 0xf, false); // row_bcast:31
    return v;
}

// dot of 32 'a' pixels (aw[0..7]) against window bytes starting at S=16+4m+OC.
template <int OC>
__device__ __forceinline__ int dot8(const unsigned* w, const unsigned* aw, int acc) {
#pragma unroll
    for (int m = 0; m < 8; ++m) {
        const int S = 16 + 4 * m + OC;
        unsigned b;
        if ((S & 3) == 0) b = w[S >> 2];
        else              b = funnel(w[(S >> 2) + 1], w[S >> 2], S & 3);
        acc = sdot4i(aw[m], b, acc);
    }
    return acc;
}

// scalar-component assignment only (vector punning into scalar arrays kills SROA)
__device__ __forceinline__ void load16w(const unsigned char* wp, unsigned* w) {
    uint4 t0 = *(const uint4*)(wp);
    uint4 t1 = *(const uint4*)(wp + 16);
    uint4 t2 = *(const uint4*)(wp + 32);
    uint4 t3 = *(const uint4*)(wp + 48);
    w[0] = t0.x;  w[1] = t0.y;  w[2] = t0.z;  w[3] = t0.w;
    w[4] = t1.x;  w[5] = t1.y;  w[6] = t1.z;  w[7] = t1.w;
    w[8] = t2.x;  w[9] = t2.y;  w[10] = t2.z; w[11] = t2.w;
    w[12] = t3.x; w[13] = t3.y; w[14] = t3.z; w[15] = t3.w;
}

__device__ __forceinline__ void load8mid(const unsigned char* wp, unsigned* w) {
    uint4 t1 = *(const uint4*)(wp + 16);
    uint4 t2 = *(const uint4*)(wp + 32);
    w[4] = t1.x;  w[5] = t1.y;  w[6] = t1.z;  w[7] = t1.w;
    w[8] = t2.x;  w[9] = t2.y;  w[10] = t2.z; w[11] = t2.w;
}

__device__ __forceinline__ unsigned pack4(float4 f, float s, float b) {
    unsigned q0 = (unsigned)(int)fmaf(f.x, s, b);
    unsigned q1 = (unsigned)(int)fmaf(f.y, s, b);
    unsigned q2 = (unsigned)(int)fmaf(f.z, s, b);
    unsigned q3 = (unsigned)(int)fmaf(f.w, s, b);
    return (((q0 & 255u)) | ((q1 & 255u) << 8) | ((q2 & 255u) << 16) | ((q3 & 255u) << 24)) ^ 0x80808080u;
}

// ---------------- kernel 1: per-image min/max partials + zero ws accums -------
__global__ __launch_bounds__(256)
void minmax_partial(const float* __restrict__ x, float* __restrict__ pmn,
                    float* __restrict__ pmx, unsigned long long* __restrict__ gacc,
                    int* __restrict__ RowS, int* __restrict__ ColS,
                    unsigned* __restrict__ dctr) {
    int img = blockIdx.y;
    int chunk = blockIdx.x;             // 64 chunks of 16384 floats
    int tid = threadIdx.x;
    if (chunk == 0) {                   // ws is poisoned each launch: zero here
        if (tid < NACC) gacc[img * NACC + tid] = 0ull;
        if (tid >= 32 && tid < 46) RowS[img * 14 + tid - 32] = 0;
        if (tid >= 64 && tid < 78) ColS[img * 14 + tid - 64] = 0;
        if (img == 0 && tid == 96) *dctr = 0u;
    }
    const float4* b4 = (const float4*)(x + (size_t)img * (H * (size_t)W) +
                                       (size_t)chunk * (H * W / 64));
    float mn = INFINITY, mx = -INFINITY;
    for (int i = tid; i < 4096; i += 256) {
        float4 v = b4[i];
        mn = fminf(mn, fminf(fminf(v.x, v.y), fminf(v.z, v.w)));
        mx = fmaxf(mx, fmaxf(fmaxf(v.x, v.y), fmaxf(v.z, v.w)));
    }
    for (int o = 32; o > 0; o >>= 1) {
        mn = fminf(mn, __shfl_down(mn, o, 64));
        mx = fmaxf(mx, __shfl_down(mx, o, 64));
    }
    __shared__ float smn[4], smx[4];
    int wave = tid >> 6, lane = tid & 63;
    if (lane == 0) { smn[wave] = mn; smx[wave] = mx; }
    __syncthreads();
    if (tid == 0) {
        mn = fminf(fminf(smn[0], smn[1]), fminf(smn[2], smn[3]));
        mx = fmaxf(fmaxf(smx[0], smx[1]), fmaxf(smx[2], smx[3]));
        pmn[img * 64 + chunk] = mn;
        pmx[img * 64 + chunk] = mx;
    }
}

// ------- kernel 2: cross terms + s^2 + borders/corners + fused finalize -------
__global__ __launch_bounds__(NTHR)
void glcm_main(const float* __restrict__ x, const float* __restrict__ pmn,
               const float* __restrict__ pmx, unsigned long long* __restrict__ gacc,
               int* __restrict__ RowS, int* __restrict__ ColS,
               int* __restrict__ cornerWS, unsigned* __restrict__ dctr,
               float* __restrict__ out) {
    __shared__ __align__(16) unsigned char tile[TROWS * TSTR];
    __shared__ int wsum[NWAVE][NACC];
    __shared__ int sRB[7], sCB[7];
    __shared__ float sms[2];
    __shared__ int lastFlag;
    int tid = threadIdx.x;
    int img = blockIdx.z;
    int gr0 = blockIdx.y * TH;
    int gc0 = blockIdx.x * TW;

    // per-block min/max finalize (identical op order every block -> identical scale)
    if (tid < 64) {
        float mn = pmn[img * 64 + tid], mx = pmx[img * 64 + tid];
        for (int o = 32; o > 0; o >>= 1) {
            mn = fminf(mn, __shfl_down(mn, o, 64));
            mx = fmaxf(mx, __shfl_down(mx, o, 64));
        }
        if (tid == 0) {
            float sc = 255.0f / (mx - mn);
            sms[0] = sc; sms[1] = -mn * sc;
        }
    }
    if (tid >= 64 && tid < 71) { sRB[tid - 64] = 0; sCB[tid - 64] = 0; }
    __syncthreads();
    float scale = sms[0], nmb = sms[1];
    const float* xi = x + (size_t)img * (H * (size_t)W);

    // stage rows gr0..gr0+70; LDS byte c <-> global col gc0-16+c; zero pad OOB
    for (int slot = tid; slot < TROWS * (TSTR / 16); slot += NTHR) {
        int rr = slot / (TSTR / 16);
        int cc = (slot - rr * (TSTR / 16)) * 16;
        int grow = gr0 + rr;
        int gcol = gc0 - 16 + cc;
        uint4 bytes = make_uint4(0u, 0u, 0u, 0u);
        if (grow < H && gcol >= 0 && gcol < W) {
            const float4* p = (const float4*)(xi + (size_t)grow * W + gcol);
            float4 f0 = p[0], f1 = p[1], f2 = p[2], f3 = p[3];
            bytes.x = pack4(f0, scale, nmb);
            bytes.y = pack4(f1, scale, nmb);
            bytes.z = pack4(f2, scale, nmb);
            bytes.w = pack4(f3, scale, nmb);
        }
        *(uint4*)(tile + rr * TSTR + cc) = bytes;
    }
    __syncthreads();

    int r = tid >> 3;             // 0..63
    int c0 = (tid & 7) * 32;      // 0..224
    const unsigned char* rowp = tile + r * TSTR + 16 + c0;   // 'a' pixels
    const unsigned char* wbase = tile + r * TSTR + c0;       // window byte S=0

    uint4 av0 = *(const uint4*)(rowp);
    uint4 av1 = *(const uint4*)(rowp + 16);
    unsigned aw[8];
    aw[0] = av0.x; aw[1] = av0.y; aw[2] = av0.z; aw[3] = av0.w;
    aw[4] = av1.x; aw[5] = av1.y; aw[6] = av1.z; aw[7] = av1.w;

    int acc[NACC];
#pragma unroll
    for (int k = 0; k < NACC; ++k) acc[k] = 0;
#pragma unroll
    for (int m = 0; m < 8; ++m) acc[16] = sdot4i(aw[m], aw[m], acc[16]);

    unsigned w[16];
    // delta = 0 : oc = 1,3,5,7 — OC 1/5 share shift-1 funnels, OC 3/7 share shift-3
    {
#pragma unroll
        for (int i = 0; i < 8; ++i) w[4 + i] = aw[i];
        uint4 t3 = *(const uint4*)(wbase + 48);
        w[12] = t3.x; w[13] = t3.y; w[14] = t3.z; w[15] = t3.w;
        unsigned f1[9], f3[9];
#pragma unroll
        for (int k = 0; k < 9; ++k) {
            f1[k] = funnel(w[5 + k], w[4 + k], 1);
            f3[k] = funnel(w[5 + k], w[4 + k], 3);
        }
#pragma unroll
        for (int m = 0; m < 8; ++m) {
            acc[0]  = sdot4i(aw[m], f1[m],     acc[0]);   // oc=1  : S=17+4m
            acc[8]  = sdot4i(aw[m], f1[m + 1], acc[8]);   // oc=5  : S=21+4m
            acc[4]  = sdot4i(aw[m], f3[m],     acc[4]);   // oc=3  : S=19+4m
            acc[12] = sdot4i(aw[m], f3[m + 1], acc[12]);  // oc=7  : S=23+4m
        }
    }
    // delta = 1 : oc = 1,0,-1
    {
        load16w(wbase + 1 * TSTR, w);
        acc[1] = dot8<1>(w, aw, acc[1]);
        acc[2] = dot8<0>(w, aw, acc[2]);
        acc[3] = dot8<-1>(w, aw, acc[3]);
    }
    // delta = 2 : oc = 2,-2 — shared shift-2 funnels
    {
        load16w(wbase + 2 * TSTR, w);
        unsigned f2[10];
#pragma unroll
        for (int k = 0; k < 10; ++k) f2[k] = funnel(w[4 + k], w[3 + k], 2);
#pragma unroll
        for (int m = 0; m < 8; ++m) {
            acc[5] = sdot4i(aw[m], f2[m + 1], acc[5]);    // oc=2  : S=18+4m
            acc[7] = sdot4i(aw[m], f2[m],     acc[7]);    // oc=-2 : S=14+4m
        }
    }
    // delta = 3 : oc = 0
    {
        load8mid(wbase + 3 * TSTR, w);
        acc[6] = dot8<0>(w, aw, acc[6]);
    }
    // delta = 4 : oc = 4,-4 (aligned, no funnels)
    {
        load16w(wbase + 4 * TSTR, w);
        acc[9]  = dot8<4>(w, aw, acc[9]);
        acc[11] = dot8<-4>(w, aw, acc[11]);
    }
    // delta = 5 : oc = 0,5,-5
    {
        load16w(wbase + 5 * TSTR, w);
        acc[10] = dot8<0>(w, aw, acc[10]);
        acc[13] = dot8<5>(w, aw, acc[13]);
        acc[15] = dot8<-5>(w, aw, acc[15]);
    }
    // delta = 7 : oc = 0
    {
        load8mid(wbase + 7 * TSTR, w);
        acc[14] = dot8<0>(w, aw, acc[14]);
    }

    // wave reduce via DPP (no LDS serialization), lane 63 holds totals
    int wv = tid >> 6, lane = tid & 63;
#pragma unroll
    for (int k = 0; k < NACC; ++k) {
        int t = wave_sum(acc[k]);
        if (lane == 63) wsum[wv][k] = t;
    }

    // border blocks: band sums of s^2 from the staged tile
    bool rowTop = (gr0 == 0), rowBot = (gr0 == H - TH);
    bool colLft = (gc0 == 0), colRgt = (gc0 == W - TW);
    if (rowTop || rowBot) {
        int base = rowTop ? 0 : TH - 7;        // rows 0-6 or 1017-1023
        for (int idx = tid; idx < 7 * 64; idx += NTHR) {
            int rr = idx >> 6, ww = idx & 63;
            unsigned v = *(const unsigned*)(tile + (base + rr) * TSTR + 16 + 4 * ww);
            atomicAdd(&sRB[rr], sdot4i(v, v, 0));
        }
    }
    if (colLft || colRgt) {
        int cb = colLft ? 16 : 265;            // cols 0-6 or 1017-1023
        if (tid < 7 * TH) {
            int rr = tid / 7, j = tid - rr * 7;
            int s = (int)(signed char)tile[rr * TSTR + cb + j];
            atomicAdd(&sCB[j], s * s);
        }
    }
    // corner 7x7 s^2 patches -> ws (c4: 0=TL,1=TR,2=BL,3=BR, oriented to corner)
    if (tid < 49) {
        int i = tid / 7, j = tid - i * 7;
        if (rowTop && colLft) {
            int s = (int)(signed char)tile[i * TSTR + 16 + j];
            cornerWS[(img * 4 + 0) * 49 + tid] = s * s;
        }
        if (rowTop && colRgt) {
            int s = (int)(signed char)tile[i * TSTR + 271 - j];
            cornerWS[(img * 4 + 1) * 49 + tid] = s * s;
        }
        if (rowBot && colLft) {
            int s = (int)(signed char)tile[(TH - 1 - i) * TSTR + 16 + j];
            cornerWS[(img * 4 + 2) * 49 + tid] = s * s;
        }
        if (rowBot && colRgt) {
            int s = (int)(signed char)tile[(TH - 1 - i) * TSTR + 271 - j];
            cornerWS[(img * 4 + 3) * 49 + tid] = s * s;
        }
    }
    __syncthreads();
    if (tid < NACC) {
        int s = 0;
#pragma unroll
        for (int w8 = 0; w8 < NWAVE; ++w8) s += wsum[w8][tid];
        atomicAdd(&gacc[img * NACC + tid], (unsigned long long)(long long)s);
    }
    if (tid < 7) {
        if (rowTop) atomicAdd(&RowS[img * 14 + tid], sRB[tid]);
        if (rowBot) atomicAdd(&RowS[img * 14 + 7 + tid], sRB[tid]);
        if (colLft) atomicAdd(&ColS[img * 14 + tid], sCB[tid]);
        if (colRgt) atomicAdd(&ColS[img * 14 + 7 + tid], sCB[tid]);
    }

    // ---- fused finalize: last block to finish computes the 512 outputs ----
    __threadfence();                 // release this block's stores + atomics
    __syncthreads();
    if (tid == 0) {
        unsigned prev = atomicAdd(dctr, 1u);
        lastFlag = (prev == (unsigned)(NBLK - 1)) ? 1 : 0;
    }
    __syncthreads();
    if (lastFlag) {                  // tid 0..511 == NIMG*NOFF outputs
        __threadfence();             // acquire: see all other blocks' results
        const int ORO[16] = {0,1,1,1, 0,2,3,2, 0,4,5,4, 0,5,7,5};
        const int OCO[16] = {1,1,0,-1, 3,2,0,-2, 5,4,0,-4, 7,5,0,-5};
        int oimg = tid >> 4, k = tid & 15;
        int orr = ORO[k], oc = OCO[k], aoc = oc < 0 ? -oc : oc;
        long long RT = 0, RB = 0, CL = 0, CR = 0;
        for (int i = 0; i < orr; ++i) {
            RT += RowS[oimg * 14 + i];
            RB += RowS[oimg * 14 + 13 - i];
        }
        for (int i = 0; i < aoc; ++i) {
            CL += ColS[oimg * 14 + i];
            CR += ColS[oimg * 14 + 13 - i];
        }
        long long CA = oc > 0 ? CR : CL;
        long long CB = oc > 0 ? CL : CR;
        // direct <=7x7 rectangle sums replace the 2D prefix (L2-hot, tiny)
        const int* crA = cornerWS + (oimg * 4 + (oc >= 0 ? 3 : 2)) * 49;
        const int* crB = cornerWS + (oimg * 4 + (oc >= 0 ? 0 : 1)) * 49;
        long long PSa = 0, PSb = 0;
        for (int i = 0; i < orr; ++i)
            for (int j = 0; j < aoc; ++j) {
                PSa += crA[i * 7 + j];
                PSb += crB[i * 7 + j];
            }
        long long corr = -(RT + RB + CA + CB) + PSa + PSb;
        long long cross = (long long)gacc[oimg * NACC + k];
        long long tsum  = (long long)gacc[oimg * NACC + 16];
        long long num = 2 * tsum + corr - 2 * cross;
        double n = (double)(H - orr) * (double)(W - aoc);
        out[tid] = (float)((double)num / n);
    }
}

extern "C" void kernel_launch(void* const* d_in, const int* in_sizes, int n_in,
                              void* d_out, int out_size, void* d_ws, size_t ws_size,
                              hipStream_t stream) {
    const float* x = (const float*)d_in[0];
    float* out = (float*)d_out;
    char* ws = (char*)d_ws;
    float* pmn = (float*)ws;                                       // 2048 f   @0
    float* pmx = (float*)(ws + 8192);                              // 2048 f   @8192
    unsigned long long* gacc = (unsigned long long*)(ws + 16384);  // 32*17 u64 @16384
    int* RowS = (int*)(ws + 20736);                                // 32*14 int
    int* ColS = (int*)(ws + 22528);                                // 32*14 int
    int* cornerWS = (int*)(ws + 24320);                            // 32*4*49 int
    unsigned* dctr = (unsigned*)(ws + 49408);                      // done counter

    minmax_partial<<<dim3(64, NIMG), 256, 0, stream>>>(x, pmn, pmx, gacc, RowS,
                                                       ColS, dctr);
    glcm_main<<<dim3(W / TW, H / TH, NIMG), NTHR, 0, stream>>>(x, pmn, pmx, gacc,
                                                               RowS, ColS, cornerWS,
                                                               dctr, out);
}

// Round 4
// 243.371 us; speedup vs baseline: 2.3566x; 2.3566x over previous
//
#include <hip/hip_runtime.h>

#define H 1024
#define W 1024
#define NIMG 32
#define NOFF 16
#define NACC 17          // 16 cross terms + 1 sum(s^2)
#define TH 64            // owned rows per block
#define TW 256           // owned cols per block
#define TROWS 71         // TH + 7 halo rows (down only)
#define TSTR 304         // LDS row stride bytes: 16 left pad + 256 + 32 right pad
#define NTHR 512
#define NWAVE 8
#define NBLK (W / TW * (H / TH) * NIMG)   // 2048 glcm blocks

__device__ __forceinline__ int sdot4i(unsigned a, unsigned b, int c) {
#if __has_builtin(__builtin_amdgcn_sdot4)
    return __builtin_amdgcn_sdot4((int)a, (int)b, c, false);
#else
    c += (int)(signed char)(a)       * (int)(signed char)(b);
    c += (int)(signed char)(a >> 8)  * (int)(signed char)(b >> 8);
    c += (int)(signed char)(a >> 16) * (int)(signed char)(b >> 16);
    c += (int)(signed char)(a >> 24) * (int)(signed char)(b >> 24);
    return c;
#endif
}

__device__ __forceinline__ unsigned funnel(unsigned hi, unsigned lo, int shiftBytes) {
#if __has_builtin(__builtin_amdgcn_alignbit)
    return __builtin_amdgcn_alignbit(hi, lo, shiftBytes * 8);
#else
    unsigned long long pair = (((unsigned long long)hi) << 32) | lo;
    return (unsigned)(pair >> (shiftBytes * 8));
#endif
}

// wave64 sum via DPP butterfly: total lands in lane 63 (pure VALU, no LDS).
__device__ __forceinline__ int wave_sum(int v) {
    v += __builtin_amdgcn_update_dpp(0, v, 0x111, 0xf, 0xf, false); // row_shr:1
    v += __builtin_amdgcn_update_dpp(0, v, 0x112, 0xf, 0xf, false); // row_shr:2
    v += __builtin_amdgcn_update_dpp(0, v, 0x114, 0xf, 0xf, false); // row_shr:4
    v += __builtin_amdgcn_update_dpp(0, v, 0x118, 0xf, 0xf, false); // row_shr:8
    v += __builtin_amdgcn_update_dpp(0, v, 0x142, 0xa, 0xf, false); // row_bcast:15
    v += __builtin_amdgcn_update_dpp(0, v, 0x143, 0xc, 0xf, false); // row_bcast:31
    return v;
}

// dot of 32 'a' pixels (aw[0..7]) against window bytes starting at S=16+4m+OC.
template <int OC>
__device__ __forceinline__ int dot8(const unsigned* w, const unsigned* aw, int acc) {
#pragma unroll
    for (int m = 0; m < 8; ++m) {
        const int S = 16 + 4 * m + OC;
        unsigned b;
        if ((S & 3) == 0) b = w[S >> 2];
        else              b = funnel(w[(S >> 2) + 1], w[S >> 2], S & 3);
        acc = sdot4i(aw[m], b, acc);
    }
    return acc;
}

// scalar-component assignment only (vector punning into scalar arrays kills SROA)
__device__ __forceinline__ void load16w(const unsigned char* wp, unsigned* w) {
    uint4 t0 = *(const uint4*)(wp);
    uint4 t1 = *(const uint4*)(wp + 16);
    uint4 t2 = *(const uint4*)(wp + 32);
    uint4 t3 = *(const uint4*)(wp + 48);
    w[0] = t0.x;  w[1] = t0.y;  w[2] = t0.z;  w[3] = t0.w;
    w[4] = t1.x;  w[5] = t1.y;  w[6] = t1.z;  w[7] = t1.w;
    w[8] = t2.x;  w[9] = t2.y;  w[10] = t2.z; w[11] = t2.w;
    w[12] = t3.x; w[13] = t3.y; w[14] = t3.z; w[15] = t3.w;
}

__device__ __forceinline__ void load8mid(const unsigned char* wp, unsigned* w) {
    uint4 t1 = *(const uint4*)(wp + 16);
    uint4 t2 = *(const uint4*)(wp + 32);
    w[4] = t1.x;  w[5] = t1.y;  w[6] = t1.z;  w[7] = t1.w;
    w[8] = t2.x;  w[9] = t2.y;  w[10] = t2.z; w[11] = t2.w;
}

__device__ __forceinline__ unsigned pack4(float4 f, float s, float b) {
    unsigned q0 = (unsigned)(int)fmaf(f.x, s, b);
    unsigned q1 = (unsigned)(int)fmaf(f.y, s, b);
    unsigned q2 = (unsigned)(int)fmaf(f.z, s, b);
    unsigned q3 = (unsigned)(int)fmaf(f.w, s, b);
    return (((q0 & 255u)) | ((q1 & 255u) << 8) | ((q2 & 255u) << 16) | ((q3 & 255u) << 24)) ^ 0x80808080u;
}

// ---------------- kernel 1: per-image min/max partials + zero ws accums -------
__global__ __launch_bounds__(256)
void minmax_partial(const float* __restrict__ x, float* __restrict__ pmn,
                    float* __restrict__ pmx, unsigned long long* __restrict__ gacc,
                    int* __restrict__ RowS, int* __restrict__ ColS,
                    unsigned* __restrict__ dctr) {
    int img = blockIdx.y;
    int chunk = blockIdx.x;             // 64 chunks of 16384 floats
    int tid = threadIdx.x;
    if (chunk == 0) {                   // ws is poisoned each launch: zero here
        if (tid < NACC) gacc[img * NACC + tid] = 0ull;
        if (tid >= 32 && tid < 46) RowS[img * 14 + tid - 32] = 0;
        if (tid >= 64 && tid < 78) ColS[img * 14 + tid - 64] = 0;
        if (img == 0 && tid == 96) *dctr = 0u;
    }
    const float4* b4 = (const float4*)(x + (size_t)img * (H * (size_t)W) +
                                       (size_t)chunk * (H * W / 64));
    float mn = INFINITY, mx = -INFINITY;
    for (int i = tid; i < 4096; i += 256) {
        float4 v = b4[i];
        mn = fminf(mn, fminf(fminf(v.x, v.y), fminf(v.z, v.w)));
        mx = fmaxf(mx, fmaxf(fmaxf(v.x, v.y), fmaxf(v.z, v.w)));
    }
    for (int o = 32; o > 0; o >>= 1) {
        mn = fminf(mn, __shfl_down(mn, o, 64));
        mx = fmaxf(mx, __shfl_down(mx, o, 64));
    }
    __shared__ float smn[4], smx[4];
    int wave = tid >> 6, lane = tid & 63;
    if (lane == 0) { smn[wave] = mn; smx[wave] = mx; }
    __syncthreads();
    if (tid == 0) {
        mn = fminf(fminf(smn[0], smn[1]), fminf(smn[2], smn[3]));
        mx = fmaxf(fmaxf(smx[0], smx[1]), fmaxf(smx[2], smx[3]));
        pmn[img * 64 + chunk] = mn;
        pmx[img * 64 + chunk] = mx;
    }
}

// ------- kernel 2: cross terms + s^2 + borders/corners + fused finalize -------
// Cross-block publication is ATOMIC-ONLY (coherent point); no __threadfence()
// anywhere (R3 measured: per-block device fences = L2 writeback/invalidate
// storm, glcm 25->410us). Writer ordering: __syncthreads() drains each wave's
// vmcnt before s_barrier, so all data atomics are complete before the dctr
// increment. Reader (last block) uses agent-scope atomic loads (cache-bypass).
__global__ __launch_bounds__(NTHR)
void glcm_main(const float* __restrict__ x, const float* __restrict__ pmn,
               const float* __restrict__ pmx, unsigned long long* __restrict__ gacc,
               int* __restrict__ RowS, int* __restrict__ ColS,
               int* __restrict__ cornerWS, unsigned* __restrict__ dctr,
               float* __restrict__ out) {
    __shared__ __align__(16) unsigned char tile[TROWS * TSTR];
    __shared__ int wsum[NWAVE][NACC];
    __shared__ int sRB[7], sCB[7];
    __shared__ float sms[2];
    __shared__ int lastFlag;
    int tid = threadIdx.x;
    int img = blockIdx.z;
    int gr0 = blockIdx.y * TH;
    int gc0 = blockIdx.x * TW;

    // per-block min/max finalize (identical op order every block -> identical scale)
    if (tid < 64) {
        float mn = pmn[img * 64 + tid], mx = pmx[img * 64 + tid];
        for (int o = 32; o > 0; o >>= 1) {
            mn = fminf(mn, __shfl_down(mn, o, 64));
            mx = fmaxf(mx, __shfl_down(mx, o, 64));
        }
        if (tid == 0) {
            float sc = 255.0f / (mx - mn);
            sms[0] = sc; sms[1] = -mn * sc;
        }
    }
    if (tid >= 64 && tid < 71) { sRB[tid - 64] = 0; sCB[tid - 64] = 0; }
    __syncthreads();
    float scale = sms[0], nmb = sms[1];
    const float* xi = x + (size_t)img * (H * (size_t)W);

    // stage rows gr0..gr0+70; LDS byte c <-> global col gc0-16+c; zero pad OOB
    for (int slot = tid; slot < TROWS * (TSTR / 16); slot += NTHR) {
        int rr = slot / (TSTR / 16);
        int cc = (slot - rr * (TSTR / 16)) * 16;
        int grow = gr0 + rr;
        int gcol = gc0 - 16 + cc;
        uint4 bytes = make_uint4(0u, 0u, 0u, 0u);
        if (grow < H && gcol >= 0 && gcol < W) {
            const float4* p = (const float4*)(xi + (size_t)grow * W + gcol);
            float4 f0 = p[0], f1 = p[1], f2 = p[2], f3 = p[3];
            bytes.x = pack4(f0, scale, nmb);
            bytes.y = pack4(f1, scale, nmb);
            bytes.z = pack4(f2, scale, nmb);
            bytes.w = pack4(f3, scale, nmb);
        }
        *(uint4*)(tile + rr * TSTR + cc) = bytes;
    }
    __syncthreads();

    int r = tid >> 3;             // 0..63
    int c0 = (tid & 7) * 32;      // 0..224
    const unsigned char* rowp = tile + r * TSTR + 16 + c0;   // 'a' pixels
    const unsigned char* wbase = tile + r * TSTR + c0;       // window byte S=0

    uint4 av0 = *(const uint4*)(rowp);
    uint4 av1 = *(const uint4*)(rowp + 16);
    unsigned aw[8];
    aw[0] = av0.x; aw[1] = av0.y; aw[2] = av0.z; aw[3] = av0.w;
    aw[4] = av1.x; aw[5] = av1.y; aw[6] = av1.z; aw[7] = av1.w;

    int acc[NACC];
#pragma unroll
    for (int k = 0; k < NACC; ++k) acc[k] = 0;
#pragma unroll
    for (int m = 0; m < 8; ++m) acc[16] = sdot4i(aw[m], aw[m], acc[16]);

    unsigned w[16];
    // delta = 0 : oc = 1,3,5,7 — OC 1/5 share shift-1 funnels, OC 3/7 share shift-3
    {
#pragma unroll
        for (int i = 0; i < 8; ++i) w[4 + i] = aw[i];
        uint4 t3 = *(const uint4*)(wbase + 48);
        w[12] = t3.x; w[13] = t3.y; w[14] = t3.z; w[15] = t3.w;
        unsigned f1[9], f3[9];
#pragma unroll
        for (int k = 0; k < 9; ++k) {
            f1[k] = funnel(w[5 + k], w[4 + k], 1);
            f3[k] = funnel(w[5 + k], w[4 + k], 3);
        }
#pragma unroll
        for (int m = 0; m < 8; ++m) {
            acc[0]  = sdot4i(aw[m], f1[m],     acc[0]);   // oc=1  : S=17+4m
            acc[8]  = sdot4i(aw[m], f1[m + 1], acc[8]);   // oc=5  : S=21+4m
            acc[4]  = sdot4i(aw[m], f3[m],     acc[4]);   // oc=3  : S=19+4m
            acc[12] = sdot4i(aw[m], f3[m + 1], acc[12]);  // oc=7  : S=23+4m
        }
    }
    // delta = 1 : oc = 1,0,-1
    {
        load16w(wbase + 1 * TSTR, w);
        acc[1] = dot8<1>(w, aw, acc[1]);
        acc[2] = dot8<0>(w, aw, acc[2]);
        acc[3] = dot8<-1>(w, aw, acc[3]);
    }
    // delta = 2 : oc = 2,-2 — shared shift-2 funnels
    {
        load16w(wbase + 2 * TSTR, w);
        unsigned f2[10];
#pragma unroll
        for (int k = 0; k < 10; ++k) f2[k] = funnel(w[4 + k], w[3 + k], 2);
#pragma unroll
        for (int m = 0; m < 8; ++m) {
            acc[5] = sdot4i(aw[m], f2[m + 1], acc[5]);    // oc=2  : S=18+4m
            acc[7] = sdot4i(aw[m], f2[m],     acc[7]);    // oc=-2 : S=14+4m
        }
    }
    // delta = 3 : oc = 0
    {
        load8mid(wbase + 3 * TSTR, w);
        acc[6] = dot8<0>(w, aw, acc[6]);
    }
    // delta = 4 : oc = 4,-4 (aligned, no funnels)
    {
        load16w(wbase + 4 * TSTR, w);
        acc[9]  = dot8<4>(w, aw, acc[9]);
        acc[11] = dot8<-4>(w, aw, acc[11]);
    }
    // delta = 5 : oc = 0,5,-5
    {
        load16w(wbase + 5 * TSTR, w);
        acc[10] = dot8<0>(w, aw, acc[10]);
        acc[13] = dot8<5>(w, aw, acc[13]);
        acc[15] = dot8<-5>(w, aw, acc[15]);
    }
    // delta = 7 : oc = 0
    {
        load8mid(wbase + 7 * TSTR, w);
        acc[14] = dot8<0>(w, aw, acc[14]);
    }

    // wave reduce via DPP (no LDS serialization), lane 63 holds totals
    int wv = tid >> 6, lane = tid & 63;
#pragma unroll
    for (int k = 0; k < NACC; ++k) {
        int t = wave_sum(acc[k]);
        if (lane == 63) wsum[wv][k] = t;
    }

    // border blocks: band sums of s^2 from the staged tile
    bool rowTop = (gr0 == 0), rowBot = (gr0 == H - TH);
    bool colLft = (gc0 == 0), colRgt = (gc0 == W - TW);
    if (rowTop || rowBot) {
        int base = rowTop ? 0 : TH - 7;        // rows 0-6 or 1017-1023
        for (int idx = tid; idx < 7 * 64; idx += NTHR) {
            int rr = idx >> 6, ww = idx & 63;
            unsigned v = *(const unsigned*)(tile + (base + rr) * TSTR + 16 + 4 * ww);
            atomicAdd(&sRB[rr], sdot4i(v, v, 0));
        }
    }
    if (colLft || colRgt) {
        int cb = colLft ? 16 : 265;            // cols 0-6 or 1017-1023
        if (tid < 7 * TH) {
            int rr = tid / 7, j = tid - rr * 7;
            int s = (int)(signed char)tile[rr * TSTR + cb + j];
            atomicAdd(&sCB[j], s * s);
        }
    }
    // corner 7x7 s^2 patches -> ws via device-scope atomicExch (coherent point)
    if (tid < 49) {
        int i = tid / 7, j = tid - i * 7;
        if (rowTop && colLft) {
            int s = (int)(signed char)tile[i * TSTR + 16 + j];
            atomicExch(&cornerWS[(img * 4 + 0) * 49 + tid], s * s);
        }
        if (rowTop && colRgt) {
            int s = (int)(signed char)tile[i * TSTR + 271 - j];
            atomicExch(&cornerWS[(img * 4 + 1) * 49 + tid], s * s);
        }
        if (rowBot && colLft) {
            int s = (int)(signed char)tile[(TH - 1 - i) * TSTR + 16 + j];
            atomicExch(&cornerWS[(img * 4 + 2) * 49 + tid], s * s);
        }
        if (rowBot && colRgt) {
            int s = (int)(signed char)tile[(TH - 1 - i) * TSTR + 271 - j];
            atomicExch(&cornerWS[(img * 4 + 3) * 49 + tid], s * s);
        }
    }
    __syncthreads();
    if (tid < NACC) {
        int s = 0;
#pragma unroll
        for (int w8 = 0; w8 < NWAVE; ++w8) s += wsum[w8][tid];
        atomicAdd(&gacc[img * NACC + tid], (unsigned long long)(long long)s);
    }
    if (tid < 7) {
        if (rowTop) atomicAdd(&RowS[img * 14 + tid], sRB[tid]);
        if (rowBot) atomicAdd(&RowS[img * 14 + 7 + tid], sRB[tid]);
        if (colLft) atomicAdd(&ColS[img * 14 + tid], sCB[tid]);
        if (colRgt) atomicAdd(&ColS[img * 14 + 7 + tid], sCB[tid]);
    }

    // ---- fused finalize: last block computes the 512 outputs (no fences) ----
    // __syncthreads drains every wave's vmcnt -> this block's atomics are
    // complete at the coherent point before tid0 increments dctr.
    __syncthreads();
    if (tid == 0) {
        unsigned prev = atomicAdd(dctr, 1u);
        lastFlag = (prev == (unsigned)(NBLK - 1)) ? 1 : 0;
    }
    __syncthreads();
    if (lastFlag) {                  // tid 0..511 == NIMG*NOFF outputs
        const int ORO[16] = {0,1,1,1, 0,2,3,2, 0,4,5,4, 0,5,7,5};
        const int OCO[16] = {1,1,0,-1, 3,2,0,-2, 5,4,0,-4, 7,5,0,-5};
        int oimg = tid >> 4, k = tid & 15;
        int orr = ORO[k], oc = OCO[k], aoc = oc < 0 ? -oc : oc;
        long long RT = 0, RB = 0, CL = 0, CR = 0;
        for (int i = 0; i < orr; ++i) {
            RT += __hip_atomic_load(&RowS[oimg * 14 + i],
                                    __ATOMIC_RELAXED, __HIP_MEMORY_SCOPE_AGENT);
            RB += __hip_atomic_load(&RowS[oimg * 14 + 13 - i],
                                    __ATOMIC_RELAXED, __HIP_MEMORY_SCOPE_AGENT);
        }
        for (int i = 0; i < aoc; ++i) {
            CL += __hip_atomic_load(&ColS[oimg * 14 + i],
                                    __ATOMIC_RELAXED, __HIP_MEMORY_SCOPE_AGENT);
            CR += __hip_atomic_load(&ColS[oimg * 14 + 13 - i],
                                    __ATOMIC_RELAXED, __HIP_MEMORY_SCOPE_AGENT);
        }
        long long CA = oc > 0 ? CR : CL;
        long long CB = oc > 0 ? CL : CR;
        // direct <=7x7 rectangle sums replace the 2D prefix (one block, tiny)
        const int* crA = cornerWS + (oimg * 4 + (oc >= 0 ? 3 : 2)) * 49;
        const int* crB = cornerWS + (oimg * 4 + (oc >= 0 ? 0 : 1)) * 49;
        long long PSa = 0, PSb = 0;
        for (int i = 0; i < orr; ++i)
            for (int j = 0; j < aoc; ++j) {
                PSa += __hip_atomic_load(&crA[i * 7 + j],
                                         __ATOMIC_RELAXED, __HIP_MEMORY_SCOPE_AGENT);
                PSb += __hip_atomic_load(&crB[i * 7 + j],
                                         __ATOMIC_RELAXED, __HIP_MEMORY_SCOPE_AGENT);
            }
        long long corr = -(RT + RB + CA + CB) + PSa + PSb;
        long long cross = (long long)__hip_atomic_load(&gacc[oimg * NACC + k],
                                    __ATOMIC_RELAXED, __HIP_MEMORY_SCOPE_AGENT);
        long long tsum  = (long long)__hip_atomic_load(&gacc[oimg * NACC + 16],
                                    __ATOMIC_RELAXED, __HIP_MEMORY_SCOPE_AGENT);
        long long num = 2 * tsum + corr - 2 * cross;
        double n = (double)(H - orr) * (double)(W - aoc);
        out[tid] = (float)((double)num / n);
    }
}

extern "C" void kernel_launch(void* const* d_in, const int* in_sizes, int n_in,
                              void* d_out, int out_size, void* d_ws, size_t ws_size,
                              hipStream_t stream) {
    const float* x = (const float*)d_in[0];
    float* out = (float*)d_out;
    char* ws = (char*)d_ws;
    float* pmn = (float*)ws;                                       // 2048 f   @0
    float* pmx = (float*)(ws + 8192);                              // 2048 f   @8192
    unsigned long long* gacc = (unsigned long long*)(ws + 16384);  // 32*17 u64 @16384
    int* RowS = (int*)(ws + 20736);                                // 32*14 int
    int* ColS = (int*)(ws + 22528);                                // 32*14 int
    int* cornerWS = (int*)(ws + 24320);                            // 32*4*49 int
    unsigned* dctr = (unsigned*)(ws + 49408);                      // done counter

    minmax_partial<<<dim3(64, NIMG), 256, 0, stream>>>(x, pmn, pmx, gacc, RowS,
                                                       ColS, dctr);
    glcm_main<<<dim3(W / TW, H / TH, NIMG), NTHR, 0, stream>>>(x, pmn, pmx, gacc,
                                                               RowS, ColS, cornerWS,
                                                               dctr, out);
}

// Round 5
// 227.263 us; speedup vs baseline: 2.5236x; 1.0709x over previous
//
#include <hip/hip_runtime.h>

#define H 1024
#define W 1024
#define NIMG 32
#define NOFF 16
#define NACC 17          // 16 cross terms + 1 sum(s^2)
#define TH 64            // owned rows per block
#define TW 256           // owned cols per block
#define TROWS 71         // TH + 7 halo rows (down only)
#define TSTR 304         // LDS row stride bytes: 16 left pad + 256 + 32 right pad
#define NTHR 512
#define NWAVE 8

__device__ __forceinline__ int sdot4i(unsigned a, unsigned b, int c) {
#if __has_builtin(__builtin_amdgcn_sdot4)
    return __builtin_amdgcn_sdot4((int)a, (int)b, c, false);
#else
    c += (int)(signed char)(a)       * (int)(signed char)(b);
    c += (int)(signed char)(a >> 8)  * (int)(signed char)(b >> 8);
    c += (int)(signed char)(a >> 16) * (int)(signed char)(b >> 16);
    c += (int)(signed char)(a >> 24) * (int)(signed char)(b >> 24);
    return c;
#endif
}

__device__ __forceinline__ unsigned funnel(unsigned hi, unsigned lo, int shiftBytes) {
#if __has_builtin(__builtin_amdgcn_alignbit)
    return __builtin_amdgcn_alignbit(hi, lo, shiftBytes * 8);
#else
    unsigned long long pair = (((unsigned long long)hi) << 32) | lo;
    return (unsigned)(pair >> (shiftBytes * 8));
#endif
}

// sum within 4-lane groups via 2 DPP steps (xor1, xor2); all 4 lanes identical.
__device__ __forceinline__ int group4_sum(int v) {
    v += __builtin_amdgcn_update_dpp(0, v, 0xB1, 0xf, 0xf, false); // quad_perm [1,0,3,2]
    v += __builtin_amdgcn_update_dpp(0, v, 0x4E, 0xf, 0xf, false); // quad_perm [2,3,0,1]
    return v;
}

// sum within 8-lane groups: group4 + row_half_mirror (lanes 0-7 self-contained).
__device__ __forceinline__ int group8_sum(int v) {
    v = group4_sum(v);
    v += __builtin_amdgcn_update_dpp(0, v, 0x141, 0xf, 0xf, false); // row_half_mirror
    return v;
}

// dot of 32 'a' pixels (aw[0..7]) against window bytes starting at S=16+4m+OC.
template <int OC>
__device__ __forceinline__ int dot8(const unsigned* w, const unsigned* aw, int acc) {
#pragma unroll
    for (int m = 0; m < 8; ++m) {
        const int S = 16 + 4 * m + OC;
        unsigned b;
        if ((S & 3) == 0) b = w[S >> 2];
        else              b = funnel(w[(S >> 2) + 1], w[S >> 2], S & 3);
        acc = sdot4i(aw[m], b, acc);
    }
    return acc;
}

// scalar-component assignment only (vector punning into scalar arrays kills SROA)
__device__ __forceinline__ void load16w(const unsigned char* wp, unsigned* w) {
    uint4 t0 = *(const uint4*)(wp);
    uint4 t1 = *(const uint4*)(wp + 16);
    uint4 t2 = *(const uint4*)(wp + 32);
    uint4 t3 = *(const uint4*)(wp + 48);
    w[0] = t0.x;  w[1] = t0.y;  w[2] = t0.z;  w[3] = t0.w;
    w[4] = t1.x;  w[5] = t1.y;  w[6] = t1.z;  w[7] = t1.w;
    w[8] = t2.x;  w[9] = t2.y;  w[10] = t2.z; w[11] = t2.w;
    w[12] = t3.x; w[13] = t3.y; w[14] = t3.z; w[15] = t3.w;
}

__device__ __forceinline__ void load8mid(const unsigned char* wp, unsigned* w) {
    uint4 t1 = *(const uint4*)(wp + 16);
    uint4 t2 = *(const uint4*)(wp + 32);
    w[4] = t1.x;  w[5] = t1.y;  w[6] = t1.z;  w[7] = t1.w;
    w[8] = t2.x;  w[9] = t2.y;  w[10] = t2.z; w[11] = t2.w;
}

__device__ __forceinline__ unsigned pack4(float4 f, float s, float b) {
    unsigned q0 = (unsigned)(int)fmaf(f.x, s, b);
    unsigned q1 = (unsigned)(int)fmaf(f.y, s, b);
    unsigned q2 = (unsigned)(int)fmaf(f.z, s, b);
    unsigned q3 = (unsigned)(int)fmaf(f.w, s, b);
    return (((q0 & 255u)) | ((q1 & 255u) << 8) | ((q2 & 255u) << 16) | ((q3 & 255u) << 24)) ^ 0x80808080u;
}

// ---------------- kernel 1: per-image min/max partials + zero ws accums -------
__global__ __launch_bounds__(256)
void minmax_partial(const float* __restrict__ x, float* __restrict__ pmn,
                    float* __restrict__ pmx, unsigned long long* __restrict__ gacc,
                    int* __restrict__ RowS, int* __restrict__ ColS) {
    int img = blockIdx.y;
    int chunk = blockIdx.x;             // 64 chunks of 16384 floats
    int tid = threadIdx.x;
    if (chunk == 0) {                   // ws is poisoned each launch: zero here
        if (tid < NACC) gacc[img * NACC + tid] = 0ull;
        if (tid >= 32 && tid < 46) RowS[img * 14 + tid - 32] = 0;
        if (tid >= 64 && tid < 78) ColS[img * 14 + tid - 64] = 0;
    }
    const float4* b4 = (const float4*)(x + (size_t)img * (H * (size_t)W) +
                                       (size_t)chunk * (H * W / 64));
    float mn = INFINITY, mx = -INFINITY;
    for (int i = tid; i < 4096; i += 256) {
        float4 v = b4[i];
        mn = fminf(mn, fminf(fminf(v.x, v.y), fminf(v.z, v.w)));
        mx = fmaxf(mx, fmaxf(fmaxf(v.x, v.y), fmaxf(v.z, v.w)));
    }
    for (int o = 32; o > 0; o >>= 1) {
        mn = fminf(mn, __shfl_down(mn, o, 64));
        mx = fmaxf(mx, __shfl_down(mx, o, 64));
    }
    __shared__ float smn[4], smx[4];
    int wave = tid >> 6, lane = tid & 63;
    if (lane == 0) { smn[wave] = mn; smx[wave] = mx; }
    __syncthreads();
    if (tid == 0) {
        mn = fminf(fminf(smn[0], smn[1]), fminf(smn[2], smn[3]));
        mx = fmaxf(fmaxf(smx[0], smx[1]), fmaxf(smx[2], smx[3]));
        pmn[img * 64 + chunk] = mn;
        pmx[img * 64 + chunk] = mx;
    }
}

// ---------------- kernel 2: cross terms + s^2 + border bands/corners ----------
__global__ __launch_bounds__(NTHR)
void glcm_main(const float* __restrict__ x, const float* __restrict__ pmn,
               const float* __restrict__ pmx, unsigned long long* __restrict__ gacc,
               int* __restrict__ RowS, int* __restrict__ ColS,
               int* __restrict__ cornerWS) {
    __shared__ __align__(16) unsigned char tile[TROWS * TSTR];
    __shared__ int wsum2[NWAVE][16][NACC];   // per 4-lane-group partials
    __shared__ int sRB[7], sCB[7];
    __shared__ float sms[2];
    int tid = threadIdx.x;
    int img = blockIdx.z;
    int gr0 = blockIdx.y * TH;
    int gc0 = blockIdx.x * TW;

    // per-block min/max finalize (identical op order every block -> identical scale)
    if (tid < 64) {
        float mn = pmn[img * 64 + tid], mx = pmx[img * 64 + tid];
        for (int o = 32; o > 0; o >>= 1) {
            mn = fminf(mn, __shfl_down(mn, o, 64));
            mx = fmaxf(mx, __shfl_down(mx, o, 64));
        }
        if (tid == 0) {
            float sc = 255.0f / (mx - mn);
            sms[0] = sc; sms[1] = -mn * sc;
        }
    }
    if (tid >= 64 && tid < 71) { sRB[tid - 64] = 0; sCB[tid - 64] = 0; }
    __syncthreads();
    float scale = sms[0], nmb = sms[1];
    const float* xi = x + (size_t)img * (H * (size_t)W);

    // stage rows gr0..gr0+70; LDS byte c <-> global col gc0-16+c; zero pad OOB
    for (int slot = tid; slot < TROWS * (TSTR / 16); slot += NTHR) {
        int rr = slot / (TSTR / 16);
        int cc = (slot - rr * (TSTR / 16)) * 16;
        int grow = gr0 + rr;
        int gcol = gc0 - 16 + cc;
        uint4 bytes = make_uint4(0u, 0u, 0u, 0u);
        if (grow < H && gcol >= 0 && gcol < W) {
            const float4* p = (const float4*)(xi + (size_t)grow * W + gcol);
            float4 f0 = p[0], f1 = p[1], f2 = p[2], f3 = p[3];
            bytes.x = pack4(f0, scale, nmb);
            bytes.y = pack4(f1, scale, nmb);
            bytes.z = pack4(f2, scale, nmb);
            bytes.w = pack4(f3, scale, nmb);
        }
        *(uint4*)(tile + rr * TSTR + cc) = bytes;
    }
    __syncthreads();

    int r = tid >> 3;             // 0..63
    int c0 = (tid & 7) * 32;      // 0..224
    const unsigned char* rowp = tile + r * TSTR + 16 + c0;   // 'a' pixels
    const unsigned char* wbase = tile + r * TSTR + c0;       // window byte S=0

    uint4 av0 = *(const uint4*)(rowp);
    uint4 av1 = *(const uint4*)(rowp + 16);
    unsigned aw[8];
    aw[0] = av0.x; aw[1] = av0.y; aw[2] = av0.z; aw[3] = av0.w;
    aw[4] = av1.x; aw[5] = av1.y; aw[6] = av1.z; aw[7] = av1.w;

    int acc[NACC];
#pragma unroll
    for (int k = 0; k < NACC; ++k) acc[k] = 0;
#pragma unroll
    for (int m = 0; m < 8; ++m) acc[16] = sdot4i(aw[m], aw[m], acc[16]);

    unsigned w[16];
    // delta = 0 : oc = 1,3,5,7 — OC 1/5 share shift-1 funnels, OC 3/7 share shift-3
    {
#pragma unroll
        for (int i = 0; i < 8; ++i) w[4 + i] = aw[i];
        uint4 t3 = *(const uint4*)(wbase + 48);
        w[12] = t3.x; w[13] = t3.y; w[14] = t3.z; w[15] = t3.w;
        unsigned f1[9], f3[9];
#pragma unroll
        for (int k = 0; k < 9; ++k) {
            f1[k] = funnel(w[5 + k], w[4 + k], 1);
            f3[k] = funnel(w[5 + k], w[4 + k], 3);
        }
#pragma unroll
        for (int m = 0; m < 8; ++m) {
            acc[0]  = sdot4i(aw[m], f1[m],     acc[0]);   // oc=1  : S=17+4m
            acc[8]  = sdot4i(aw[m], f1[m + 1], acc[8]);   // oc=5  : S=21+4m
            acc[4]  = sdot4i(aw[m], f3[m],     acc[4]);   // oc=3  : S=19+4m
            acc[12] = sdot4i(aw[m], f3[m + 1], acc[12]);  // oc=7  : S=23+4m
        }
    }
    // delta = 1 : oc = 1,0,-1
    {
        load16w(wbase + 1 * TSTR, w);
        acc[1] = dot8<1>(w, aw, acc[1]);
        acc[2] = dot8<0>(w, aw, acc[2]);
        acc[3] = dot8<-1>(w, aw, acc[3]);
    }
    // delta = 2 : oc = 2,-2 — shared shift-2 funnels
    {
        load16w(wbase + 2 * TSTR, w);
        unsigned f2[10];
#pragma unroll
        for (int k = 0; k < 10; ++k) f2[k] = funnel(w[4 + k], w[3 + k], 2);
#pragma unroll
        for (int m = 0; m < 8; ++m) {
            acc[5] = sdot4i(aw[m], f2[m + 1], acc[5]);    // oc=2  : S=18+4m
            acc[7] = sdot4i(aw[m], f2[m],     acc[7]);    // oc=-2 : S=14+4m
        }
    }
    // delta = 3 : oc = 0
    {
        load8mid(wbase + 3 * TSTR, w);
        acc[6] = dot8<0>(w, aw, acc[6]);
    }
    // delta = 4 : oc = 4,-4 (aligned, no funnels)
    {
        load16w(wbase + 4 * TSTR, w);
        acc[9]  = dot8<4>(w, aw, acc[9]);
        acc[11] = dot8<-4>(w, aw, acc[11]);
    }
    // delta = 5 : oc = 0,5,-5
    {
        load16w(wbase + 5 * TSTR, w);
        acc[10] = dot8<0>(w, aw, acc[10]);
        acc[13] = dot8<5>(w, aw, acc[13]);
        acc[15] = dot8<-5>(w, aw, acc[15]);
    }
    // delta = 7 : oc = 0
    {
        load8mid(wbase + 7 * TSTR, w);
        acc[14] = dot8<0>(w, aw, acc[14]);
    }

    // ---- cheap cross-lane reduce: 2 DPP steps to 4-lane groups, leader lanes
    // write all 17 statically-indexed partials (no runtime reg indexing). ----
    int wv = tid >> 6, lane = tid & 63;
    int t[NACC];
#pragma unroll
    for (int k = 0; k < NACC; ++k) t[k] = group4_sum(acc[k]);
    if ((lane & 3) == 0) {
        int g = lane >> 2;                   // 0..15
#pragma unroll
        for (int k = 0; k < NACC; ++k) wsum2[wv][g][k] = t[k];
    }

    // border blocks: band sums of s^2 from the staged tile
    bool rowTop = (gr0 == 0), rowBot = (gr0 == H - TH);
    bool colLft = (gc0 == 0), colRgt = (gc0 == W - TW);
    if (rowTop || rowBot) {
        int base = rowTop ? 0 : TH - 7;        // rows 0-6 or 1017-1023
        for (int idx = tid; idx < 7 * 64; idx += NTHR) {
            int rr = idx >> 6, ww = idx & 63;
            unsigned v = *(const unsigned*)(tile + (base + rr) * TSTR + 16 + 4 * ww);
            atomicAdd(&sRB[rr], sdot4i(v, v, 0));
        }
    }
    if (colLft || colRgt) {
        int cb = colLft ? 16 : 265;            // cols 0-6 or 1017-1023
        if (tid < 7 * TH) {
            int rr = tid / 7, j = tid - rr * 7;
            int s = (int)(signed char)tile[rr * TSTR + cb + j];
            atomicAdd(&sCB[j], s * s);
        }
    }
    // corner 7x7 s^2 patches -> ws (c4: 0=TL,1=TR,2=BL,3=BR, oriented to corner)
    if (tid < 49) {
        int i = tid / 7, j = tid - i * 7;
        if (rowTop && colLft) {
            int s = (int)(signed char)tile[i * TSTR + 16 + j];
            cornerWS[(img * 4 + 0) * 49 + tid] = s * s;
        }
        if (rowTop && colRgt) {
            int s = (int)(signed char)tile[i * TSTR + 271 - j];
            cornerWS[(img * 4 + 1) * 49 + tid] = s * s;
        }
        if (rowBot && colLft) {
            int s = (int)(signed char)tile[(TH - 1 - i) * TSTR + 16 + j];
            cornerWS[(img * 4 + 2) * 49 + tid] = s * s;
        }
        if (rowBot && colRgt) {
            int s = (int)(signed char)tile[(TH - 1 - i) * TSTR + 271 - j];
            cornerWS[(img * 4 + 3) * 49 + tid] = s * s;
        }
    }
    __syncthreads();
    // combine: thread block tid = k*8 + wv (k<17, wv<8): sum 16 groups of its
    // wave, then 8-lane DPP sum across wv (contiguous lanes k*8..k*8+7).
    if (tid < NACC * 8) {
        int k = tid >> 3, wvv = tid & 7;
        int s = 0;
#pragma unroll
        for (int g = 0; g < 16; ++g) s += wsum2[wvv][g][k];
        s = group8_sum(s);                    // lanes k*8..k*8+7 hold total
        if (wvv == 0)
            atomicAdd(&gacc[img * NACC + k], (unsigned long long)(long long)s);
    }
    if (tid < 7) {
        if (rowTop) atomicAdd(&RowS[img * 14 + tid], sRB[tid]);
        if (rowBot) atomicAdd(&RowS[img * 14 + 7 + tid], sRB[tid]);
        if (colLft) atomicAdd(&ColS[img * 14 + tid], sCB[tid]);
        if (colRgt) atomicAdd(&ColS[img * 14 + 7 + tid], sCB[tid]);
    }
}

// ---------------- kernel 3: corners prefix (register-resident) + combine ------
__global__ __launch_bounds__(512)
void finalize_k(const unsigned long long* __restrict__ gacc,
                const int* __restrict__ RowS, const int* __restrict__ ColS,
                const int* __restrict__ cornerWS, float* __restrict__ out) {
    __shared__ int cps[NIMG][4][8][8];
    int tid = threadIdx.x;
    if (tid < NIMG * 4) {   // 2D prefix in registers (no LDS dependent chain)
        int img = tid >> 2, c4 = tid & 3;
        const int* cr = cornerWS + tid * 49;
        int prev[8];
#pragma unroll
        for (int c = 0; c < 8; ++c) { prev[c] = 0; cps[img][c4][0][c] = 0; }
#pragma unroll
        for (int rr = 1; rr < 8; ++rr) {
            int cur[8];
            cur[0] = 0;
#pragma unroll
            for (int c = 1; c < 8; ++c)
                cur[c] = prev[c] + cur[c - 1] - prev[c - 1] + cr[(rr - 1) * 7 + (c - 1)];
#pragma unroll
            for (int c = 0; c < 8; ++c) { cps[img][c4][rr][c] = cur[c]; prev[c] = cur[c]; }
        }
    }
    __syncthreads();
    if (tid < NIMG * NOFF) {
        const int ORO[16] = {0,1,1,1, 0,2,3,2, 0,4,5,4, 0,5,7,5};
        const int OCO[16] = {1,1,0,-1, 3,2,0,-2, 5,4,0,-4, 7,5,0,-5};
        int img = tid >> 4, k = tid & 15;
        int orr = ORO[k], oc = OCO[k], aoc = oc < 0 ? -oc : oc;
        long long RT = 0, RB = 0, CL = 0, CR = 0;
        for (int i = 0; i < orr; ++i) { RT += RowS[img * 14 + i]; RB += RowS[img * 14 + 13 - i]; }
        for (int i = 0; i < aoc; ++i) { CL += ColS[img * 14 + i]; CR += ColS[img * 14 + 13 - i]; }
        long long CA = oc > 0 ? CR : CL;
        long long CB = oc > 0 ? CL : CR;
        long long PSa = (oc >= 0) ? cps[img][3][orr][aoc] : cps[img][2][orr][aoc];
        long long PSb = (oc >= 0) ? cps[img][0][orr][aoc] : cps[img][1][orr][aoc];
        long long corr = -(RT + RB + CA + CB) + PSa + PSb;
        long long cross = (long long)gacc[img * NACC + k];
        long long tsum  = (long long)gacc[img * NACC + 16];
        long long num = 2 * tsum + corr - 2 * cross;
        double n = (double)(H - orr) * (double)(W - aoc);
        out[tid] = (float)((double)num / n);
    }
}

extern "C" void kernel_launch(void* const* d_in, const int* in_sizes, int n_in,
                              void* d_out, int out_size, void* d_ws, size_t ws_size,
                              hipStream_t stream) {
    const float* x = (const float*)d_in[0];
    float* out = (float*)d_out;
    char* ws = (char*)d_ws;
    float* pmn = (float*)ws;                                       // 2048 f   @0
    float* pmx = (float*)(ws + 8192);                              // 2048 f   @8192
    unsigned long long* gacc = (unsigned long long*)(ws + 16384);  // 32*17 u64 @16384
    int* RowS = (int*)(ws + 20736);                                // 32*14 int
    int* ColS = (int*)(ws + 22528);                                // 32*14 int
    int* cornerWS = (int*)(ws + 24320);                            // 32*4*49 int

    minmax_partial<<<dim3(64, NIMG), 256, 0, stream>>>(x, pmn, pmx, gacc, RowS, ColS);
    glcm_main<<<dim3(W / TW, H / TH, NIMG), NTHR, 0, stream>>>(x, pmn, pmx, gacc,
                                                               RowS, ColS, cornerWS);
    finalize_k<<<1, 512, 0, stream>>>(gacc, RowS, ColS, cornerWS, out);
}